// Round 9
// baseline (6855.907 us; speedup 1.0000x reference)
//
#include <hip/hip_runtime.h>
#include <hip/hip_bf16.h>

// Neural CDE forward, R9: R7 structure (256 blocks x 512 thr x 8 rows, fused-VF,
// spill-free) + per-wave 3-slot global_load_lds fragment ring so B-stream
// latency is hidden in LDS instead of VGPRs. Counted vmcnt(2*NT) per ks-iter
// (never 0 mid-loop); lgkmcnt(0)+sched_barrier before recycling a slot.
// Layers via mfma_f32_16x16x32_bf16, dup-row A (row=lane&7; C rows 8..15 dup,
// skipped). L3 fuses tanh + D-contraction via LDS atomicAdd into vf[8][128].
// RK4 (3/8) state in registers.

typedef __attribute__((ext_vector_type(4))) float f32x4;
typedef __attribute__((ext_vector_type(8))) short s16x8;

#define N_AG  2048
#define D_IN  10
#define NPTS  46
#define RROWS 8

#define OFF_W0P 0
#define OFF_W1P (128 * 512)
#define OFF_W2P (OFF_W1P + 512 * 512)
#define OFF_W3P (OFF_W2P + 512 * 512)
#define OFF_END (OFF_W3P + 512 * 1280)   // ushorts

#define VMWAIT(N) do { asm volatile("s_waitcnt vmcnt(" #N ")" ::: "memory"); \
                       __builtin_amdgcn_sched_barrier(0); } while (0)
#define LGKM0     do { asm volatile("s_waitcnt lgkmcnt(0)" ::: "memory");    \
                       __builtin_amdgcn_sched_barrier(0); } while (0)

__device__ __forceinline__ ushort f2bf(float v) {
  __hip_bfloat16 h = __float2bfloat16(v);
  return *reinterpret_cast<ushort*>(&h);
}

// async global->LDS, 16B per lane: wave-uniform LDS base + lane*16
__device__ __forceinline__ void gload_lds16(const void* g, void* l) {
  __builtin_amdgcn_global_load_lds(
      (const __attribute__((address_space(1))) unsigned int*)g,
      (__attribute__((address_space(3))) unsigned int*)l, 16, 0, 0);
}

// Pack W (O x K fp32, row-major) into MFMA B-fragment order (verified R2-R8):
// packed[((ct*KS+ks)*64 + lane)*8 + j] = bf16(W[col][k]),
// col = ct*16 + (lane&15), k = ks*32 + (lane>>4)*8 + j.
__global__ void pack_w(const float* __restrict__ W, ushort* __restrict__ Wp,
                       int O, int K) {
  int idx = blockIdx.x * blockDim.x + threadIdx.x;
  if (idx >= O * K) return;
  int j    = idx & 7;
  int lane = (idx >> 3) & 63;
  int rest = idx >> 9;
  int KS   = K >> 5;
  int ks   = rest % KS;
  int ct   = rest / KS;
  int col  = (ct << 4) + (lane & 15);
  int k    = (ks << 5) + ((lane >> 4) << 3) + j;
  Wp[idx]  = f2bf(W[col * K + k]);
}

// Natural cubic spline derivative table (verified R1-R8).
__global__ void spline_dx_k(const float* __restrict__ x, float* __restrict__ dX) {
  int idx = blockIdx.x * blockDim.x + threadIdx.x;
  if (idx >= N_AG * D_IN) return;
  int n = idx / D_IN;
  int d = idx - n * D_IN;

  float xv[16];
#pragma unroll
  for (int t = 0; t < 16; ++t) xv[t] = x[n * 160 + t * 10 + d];

  float cp[15], dp[15], M[16];
  {
    float rhs = 6.0f * (xv[2] - 2.0f * xv[1] + xv[0]);
    cp[1] = 0.25f;
    dp[1] = rhs * 0.25f;
#pragma unroll
    for (int i = 2; i <= 14; ++i) {
      rhs = 6.0f * (xv[i + 1] - 2.0f * xv[i] + xv[i - 1]);
      float m = 1.0f / (4.0f - cp[i - 1]);
      cp[i] = m;
      dp[i] = (rhs - dp[i - 1]) * m;
    }
    M[0] = 0.0f; M[15] = 0.0f;
    M[14] = dp[14];
#pragma unroll
    for (int i = 13; i >= 1; --i) M[i] = dp[i] - cp[i] * M[i + 1];
  }

#pragma unroll
  for (int p = 0; p < NPTS; ++p) {
    int i; float u;
    if (p < 45) { i = p / 3; u = (float)(p % 3) * (1.0f / 3.0f); }
    else        { i = 14;    u = 1.0f; }
    float b = (xv[i + 1] - xv[i]) - (2.0f * M[i] + M[i + 1]) * (1.0f / 6.0f);
    dX[p * (N_AG * D_IN) + idx] = b + M[i] * u + (M[i + 1] - M[i]) * (u * u * 0.5f);
  }
}

// One FC slice via 3-slot LDS fragment ring. Batch = NT fragments (one ks).
// ring: this wave's region, slot stride NT*512 ushorts, 3 slots.
// VF=false: relu -> swizzled bf16 store. VF=true: tanh -> vf atomicAdd.
template <int KS, int NT, bool VF>
__device__ __forceinline__ void fc_ring(const ushort* __restrict__ Ain, int arowb,
                                        const ushort* __restrict__ Wp,
                                        const float* __restrict__ bias_lds,
                                        ushort* __restrict__ Outb, int orowb,
                                        float (*__restrict__ vf)[128],
                                        const float (*__restrict__ dXs)[D_IN],
                                        ushort* __restrict__ ring,
                                        int w, int lane, int tbase) {
  static_assert(KS >= 3 && (NT == 2 || NT == 4), "");
  f32x4 acc[NT];
#pragma unroll
  for (int t = 0; t < NT; ++t) acc[t] = (f32x4){0.f, 0.f, 0.f, 0.f};

  const int row8 = lane & 7;
  const int g    = lane >> 4;
  const char* abase = (const char*)Ain + row8 * arowb;
  const int aswz = row8 << 4;

#define ISSUE(bb)                                                              \
  {                                                                            \
    ushort* s_ = ring + ((bb) % 3) * (NT * 512);                               \
    _Pragma("unroll")                                                          \
    for (int t = 0; t < NT; ++t) {                                             \
      int ct_ = w + ((tbase + t) << 3);                                        \
      gload_lds16(Wp + (((ct_ * KS + (bb)) * 64 + lane) << 3), s_ + t * 512);  \
    }                                                                          \
  }

  ISSUE(0) ISSUE(1) ISSUE(2)

#pragma unroll
  for (int ks = 0; ks < KS; ++ks) {
    const int rem = KS - 1 - ks;
    if (rem >= 2)      { if constexpr (NT == 4) VMWAIT(8); else VMWAIT(4); }
    else if (rem == 1) { if constexpr (NT == 4) VMWAIT(4); else VMWAIT(2); }
    else               VMWAIT(0);

    const ushort* s = ring + (ks % 3) * (NT * 512);
    s16x8 a = *(const s16x8*)(abase + (((ks << 6) + (g << 4)) ^ aswz));
    s16x8 bfr[NT];
#pragma unroll
    for (int t = 0; t < NT; ++t) bfr[t] = *(const s16x8*)(s + t * 512 + lane * 8);
    LGKM0;                      // reads done before slot is recycled
    if (ks + 3 < KS) ISSUE(ks + 3)
#pragma unroll
    for (int t = 0; t < NT; ++t)
      acc[t] = __builtin_amdgcn_mfma_f32_16x16x32_bf16(a, bfr[t], acc[t], 0, 0, 0);
  }
#undef ISSUE

#pragma unroll
  for (int t = 0; t < NT; ++t) {
    int ct  = w + ((tbase + t) << 3);
    int col = (ct << 4) + (lane & 15);
    float bb = bias_lds[col];
#pragma unroll
    for (int r = 0; r < 4; ++r) {
      int orow = (g << 2) + r;
      if (orow < RROWS) {              // rows 8..15 dup of 0..7: skip
        float v = acc[t][r] + bb;
        if (!VF) {
          v = fmaxf(v, 0.f);
          int byte = (orow * orowb + (col << 1)) ^ (orow << 4);
          *(ushort*)((char*)Outb + byte) = f2bf(v);
        } else {
          v = 1.0f - 2.0f * __builtin_amdgcn_rcpf(__expf(2.0f * v) + 1.0f);
          int e = col / 10, d = col - e * 10;
          atomicAdd(&vf[orow][e], v * dXs[orow][d]);
        }
      }
    }
  }
}

__global__ __launch_bounds__(512, 2) void cde_mfma(
    const float* __restrict__ x, const int* __restrict__ mask,
    const float* __restrict__ We, const float* __restrict__ be,
    const float* __restrict__ b0, const float* __restrict__ b1,
    const float* __restrict__ b2, const float* __restrict__ b3,
    const ushort* __restrict__ Wp, const float* __restrict__ dX,
    float* __restrict__ out) {
  const int tid  = threadIdx.x;
  const int lane = tid & 63;
  const int w    = tid >> 6;
  const int n0   = blockIdx.x * RROWS;

  __shared__ ushort A0[RROWS * 128];     // 2 KB, swizzled bf16
  __shared__ ushort H1[RROWS * 512];     // 8 KB
  __shared__ ushort H2[RROWS * 512];     // 8 KB
  __shared__ ushort RING[8][3 * 4 * 512]; // 96 KB: per-wave 3 slots x <=4 frags
  __shared__ float  BL[2816];            // b0|b1|b2|b3
  __shared__ float  vf[RROWS][128];      // fused contraction accumulator
  __shared__ float  dXs[RROWS][D_IN];

  float zreg[2], k1r[2], k2r[2], k3r[2];

  // biases -> LDS (once)
  {
    int i = tid;
    BL[i] = b0[i]; BL[512 + i] = b1[i]; BL[1024 + i] = b2[i];
    BL[1536 + i] = b3[i];
    BL[2048 + i] = b3[512 + i];
    if (tid < 256) BL[2560 + tid] = b3[1024 + tid];
  }

  // z0 = x[:,0,:] @ We^T + be   (2 (row,e) elements per thread)
#pragma unroll
  for (int q = 0; q < 2; ++q) {
    int idx = (q << 9) + tid;
    int e = idx & 127, row = idx >> 7;
    float acc = be[e];
    const float* xr = x + (n0 + row) * 160;
#pragma unroll
    for (int d = 0; d < 10; ++d) acc = fmaf(xr[d], We[e * 10 + d], acc);
    zreg[q] = acc;
    int byte = ((row << 8) + (e << 1)) ^ (row << 4);
    *(ushort*)((char*)A0 + byte) = f2bf(acc);
  }
  __syncthreads();

  ushort* ring = &RING[w][0];

#pragma unroll 1
  for (int s = 0; s < 15; ++s) {
#pragma unroll 1
    for (int st = 0; st < 4; ++st) {
      if (tid < RROWS * D_IN) {
        int p = (st < 3) ? (3 * s + st) : ((s < 14) ? (3 * s + 3) : 45);
        dXs[tid / 10][tid % 10] = dX[p * (N_AG * D_IN) + n0 * 10 + tid];
      }
      fc_ring<4, 4, false>(A0, 256, Wp + OFF_W0P, BL, H1, 1024, vf, dXs, ring, w, lane, 0);
      __syncthreads();
      fc_ring<16, 4, false>(H1, 1024, Wp + OFF_W1P, BL + 512, H2, 1024, vf, dXs, ring, w, lane, 0);
      __syncthreads();
      fc_ring<16, 4, false>(H2, 1024, Wp + OFF_W2P, BL + 1024, H1, 1024, vf, dXs, ring, w, lane, 0);
      // zero vf for this stage's contraction (disjoint; synced below)
      ((float*)vf)[tid] = 0.f;
      ((float*)vf)[512 + tid] = 0.f;
      __syncthreads();
      fc_ring<16, 4, true>(H1, 1024, Wp + OFF_W3P, BL + 1536, nullptr, 0, vf, dXs, ring, w, lane, 0);
      fc_ring<16, 4, true>(H1, 1024, Wp + OFF_W3P, BL + 1536, nullptr, 0, vf, dXs, ring, w, lane, 4);
      fc_ring<16, 2, true>(H1, 1024, Wp + OFF_W3P, BL + 1536, nullptr, 0, vf, dXs, ring, w, lane, 8);
      __syncthreads();

      // RK4 (3/8 rule), state in registers
#pragma unroll
      for (int q = 0; q < 2; ++q) {
        int idx = (q << 9) + tid;
        int e = idx & 127, row = idx >> 7;
        float dv = vf[row][e];
        float z = zreg[q], zin;
        if (st == 0)      { k1r[q] = dv; zin = z + dv * (1.f / 3.f); }
        else if (st == 1) { k2r[q] = dv; zin = z + dv - k1r[q] * (1.f / 3.f); }
        else if (st == 2) { k3r[q] = dv; zin = z + k1r[q] - k2r[q] + dv; }
        else {
          z += (k1r[q] + 3.f * (k2r[q] + k3r[q]) + dv) * 0.125f;
          zreg[q] = z; zin = z;
        }
        int byte = ((row << 8) + (e << 1)) ^ (row << 4);
        *(ushort*)((char*)A0 + byte) = f2bf(zin);
      }
      __syncthreads();
    }
  }

#pragma unroll
  for (int q = 0; q < 2; ++q) {
    int idx = (q << 9) + tid;
    int e = idx & 127, row = idx >> 7;
    out[(n0 + row) * 128 + e] = (mask[n0 + row] != 0) ? zreg[q] : 0.f;
  }
}

extern "C" void kernel_launch(void* const* d_in, const int* in_sizes, int n_in,
                              void* d_out, int out_size, void* d_ws, size_t ws_size,
                              hipStream_t stream) {
  const float* x    = (const float*)d_in[1];
  const int*   mask = (const int*)d_in[2];
  const float* We   = (const float*)d_in[3];
  const float* be   = (const float*)d_in[4];
  const float* W0   = (const float*)d_in[5];
  const float* b0   = (const float*)d_in[6];
  const float* W1   = (const float*)d_in[7];
  const float* b1   = (const float*)d_in[8];
  const float* W2   = (const float*)d_in[9];
  const float* b2   = (const float*)d_in[10];
  const float* W3   = (const float*)d_in[11];
  const float* b3   = (const float*)d_in[12];
  float* out = (float*)d_out;

  ushort* wp = (ushort*)d_ws;
  float*  dX = (float*)((char*)d_ws + (size_t)OFF_END * 2);

  pack_w<<<(128 * 512 + 255) / 256, 256, 0, stream>>>(W0, wp + OFF_W0P, 512, 128);
  pack_w<<<(512 * 512 + 255) / 256, 256, 0, stream>>>(W1, wp + OFF_W1P, 512, 512);
  pack_w<<<(512 * 512 + 255) / 256, 256, 0, stream>>>(W2, wp + OFF_W2P, 512, 512);
  pack_w<<<(512 * 1280 + 255) / 256, 256, 0, stream>>>(W3, wp + OFF_W3P, 1280, 512);
  spline_dx_k<<<(N_AG * D_IN + 255) / 256, 256, 0, stream>>>(x, dX);
  cde_mfma<<<256, 512, 0, stream>>>(x, mask, We, be, b0, b1, b2, b3, wp, dX, out);
}

// Round 11
// 3116.816 us; speedup vs baseline: 2.1997x; 2.1997x over previous
//
#include <hip/hip_runtime.h>
#include <hip/hip_bf16.h>

// Neural CDE forward, R10 resubmit (R10 bench was lost to a GPU-broker timeout).
// R7 structure (256 blocks x 512 thr x 8 rows, fused-VF) + register-disciplined
// 3-slot global_load_lds ring per wave.
// vs R9 (which spilled: 281MB scratch): ks-loop rolled (#pragma unroll 1),
// 4 loop-invariant per-lane base pointers (issue addr = gp[t] + (ks+3)*512),
// no sched_barrier, peeled 2-iter tail for literal vmcnt immediates (8/4/0).
// Layers via mfma_f32_16x16x32_bf16, dup-row A (row=lane&7; C rows 8..15 dup,
// skipped). L3 fuses tanh + D-contraction via LDS atomicAdd into vf[8][128].
// RK4 (3/8) state in registers.

typedef __attribute__((ext_vector_type(4))) float f32x4;
typedef __attribute__((ext_vector_type(8))) short s16x8;

#define N_AG  2048
#define D_IN  10
#define NPTS  46
#define RROWS 8

#define OFF_W0P 0
#define OFF_W1P (128 * 512)
#define OFF_W2P (OFF_W1P + 512 * 512)
#define OFF_W3P (OFF_W2P + 512 * 512)
#define OFF_END (OFF_W3P + 512 * 1280)   // ushorts

__device__ __forceinline__ ushort f2bf(float v) {
  __hip_bfloat16 h = __float2bfloat16(v);
  return *reinterpret_cast<ushort*>(&h);
}

template <int N>
__device__ __forceinline__ void vmwait() {
  if constexpr (N == 0)      asm volatile("s_waitcnt vmcnt(0)" ::: "memory");
  else if constexpr (N == 2) asm volatile("s_waitcnt vmcnt(2)" ::: "memory");
  else if constexpr (N == 4) asm volatile("s_waitcnt vmcnt(4)" ::: "memory");
  else                       asm volatile("s_waitcnt vmcnt(8)" ::: "memory");
}
__device__ __forceinline__ void lgkm0() {
  asm volatile("s_waitcnt lgkmcnt(0)" ::: "memory");
}

// async global->LDS, 16B per lane: per-lane global addr, wave-uniform LDS base.
__device__ __forceinline__ void gload_lds16(const void* g, void* l) {
  __builtin_amdgcn_global_load_lds(
      (const __attribute__((address_space(1))) unsigned int*)g,
      (__attribute__((address_space(3))) unsigned int*)l, 16, 0, 0);
}

// Pack W (O x K fp32, row-major) into MFMA B-fragment order (verified R2-R9):
// packed[((ct*KS+ks)*64 + lane)*8 + j] = bf16(W[col][k]),
// col = ct*16 + (lane&15), k = ks*32 + (lane>>4)*8 + j.
__global__ void pack_w(const float* __restrict__ W, ushort* __restrict__ Wp,
                       int O, int K) {
  int idx = blockIdx.x * blockDim.x + threadIdx.x;
  if (idx >= O * K) return;
  int j    = idx & 7;
  int lane = (idx >> 3) & 63;
  int rest = idx >> 9;
  int KS   = K >> 5;
  int ks   = rest % KS;
  int ct   = rest / KS;
  int col  = (ct << 4) + (lane & 15);
  int k    = (ks << 5) + ((lane >> 4) << 3) + j;
  Wp[idx]  = f2bf(W[col * K + k]);
}

// Natural cubic spline derivative table (verified R1-R9).
__global__ void spline_dx_k(const float* __restrict__ x, float* __restrict__ dX) {
  int idx = blockIdx.x * blockDim.x + threadIdx.x;
  if (idx >= N_AG * D_IN) return;
  int n = idx / D_IN;
  int d = idx - n * D_IN;

  float xv[16];
#pragma unroll
  for (int t = 0; t < 16; ++t) xv[t] = x[n * 160 + t * 10 + d];

  float cp[15], dp[15], M[16];
  {
    float rhs = 6.0f * (xv[2] - 2.0f * xv[1] + xv[0]);
    cp[1] = 0.25f;
    dp[1] = rhs * 0.25f;
#pragma unroll
    for (int i = 2; i <= 14; ++i) {
      rhs = 6.0f * (xv[i + 1] - 2.0f * xv[i] + xv[i - 1]);
      float m = 1.0f / (4.0f - cp[i - 1]);
      cp[i] = m;
      dp[i] = (rhs - dp[i - 1]) * m;
    }
    M[0] = 0.0f; M[15] = 0.0f;
    M[14] = dp[14];
#pragma unroll
    for (int i = 13; i >= 1; --i) M[i] = dp[i] - cp[i] * M[i + 1];
  }

#pragma unroll
  for (int p = 0; p < NPTS; ++p) {
    int i; float u;
    if (p < 45) { i = p / 3; u = (float)(p % 3) * (1.0f / 3.0f); }
    else        { i = 14;    u = 1.0f; }
    float b = (xv[i + 1] - xv[i]) - (2.0f * M[i] + M[i + 1]) * (1.0f / 6.0f);
    dX[p * (N_AG * D_IN) + idx] = b + M[i] * u + (M[i + 1] - M[i]) * (u * u * 0.5f);
  }
}

// One FC slice via 3-slot LDS ring (slot = NT 1KB fragments, ring recycled
// every 3 ks-steps; prefetch distance 2 batches).
// VF=false: relu -> swizzled bf16 store. VF=true: tanh -> vf atomicAdd.
template <int KS, int NT, bool VF>
__device__ __forceinline__ void fc_ring(const ushort* __restrict__ Ain, int arowb,
                                        const ushort* __restrict__ Wp,
                                        const float* __restrict__ bias_lds,
                                        ushort* __restrict__ Outb, int orowb,
                                        float (*__restrict__ vf)[128],
                                        const float (*__restrict__ dXs)[D_IN],
                                        ushort* __restrict__ ring,
                                        int w, int lane, int tbase) {
  static_assert(KS >= 4 && (NT == 2 || NT == 4), "");
  constexpr int SLOT = NT * 512;            // ushorts per slot
  constexpr int WMAIN = (NT == 4) ? 8 : 4;  // 2 batches in flight behind
  constexpr int WP1   = (NT == 4) ? 4 : 2;  // 1 batch behind

  f32x4 acc[NT];
#pragma unroll
  for (int t = 0; t < NT; ++t) acc[t] = (f32x4){0.f, 0.f, 0.f, 0.f};

  const int row8 = lane & 7;
  const int g    = lane >> 4;
  const char* abase = (const char*)Ain + row8 * arowb;
  const int aswz = row8 << 4;

  // loop-invariant per-lane global bases; batch b lives at gp[t] + b*512
  const ushort* gp[NT];
#pragma unroll
  for (int t = 0; t < NT; ++t)
    gp[t] = Wp + (size_t)(w + ((tbase + t) << 3)) * KS * 512 + lane * 8;

  // prologue: fill 3 slots (batches 0,1,2)
#pragma unroll
  for (int b = 0; b < 3; ++b)
#pragma unroll
    for (int t = 0; t < NT; ++t)
      gload_lds16(gp[t] + b * 512, ring + b * SLOT + t * 512);

  int slot = 0;
#pragma unroll 1
  for (int ks = 0; ks < KS - 2; ++ks) {
    vmwait<WMAIN>();                          // batch ks landed
    const ushort* s = ring + slot * SLOT;
    s16x8 a = *(const s16x8*)(abase + (((ks << 6) + (g << 4)) ^ aswz));
    s16x8 bfr[NT];
#pragma unroll
    for (int t = 0; t < NT; ++t) bfr[t] = *(const s16x8*)(s + t * 512 + lane * 8);
    lgkm0();                                  // reads retired before slot refill
    if (ks + 3 < KS) {
#pragma unroll
      for (int t = 0; t < NT; ++t)
        gload_lds16(gp[t] + (ks + 3) * 512, ring + slot * SLOT + t * 512);
    }
#pragma unroll
    for (int t = 0; t < NT; ++t)
      acc[t] = __builtin_amdgcn_mfma_f32_16x16x32_bf16(a, bfr[t], acc[t], 0, 0, 0);
    slot = (slot == 2) ? 0 : slot + 1;
  }
  // peeled tail: ks = KS-2 (1 batch behind), ks = KS-1 (drain)
#pragma unroll
  for (int p = 0; p < 2; ++p) {
    const int ks = KS - 2 + p;
    if (p == 0) vmwait<WP1>(); else vmwait<0>();
    const ushort* s = ring + slot * SLOT;
    s16x8 a = *(const s16x8*)(abase + (((ks << 6) + (g << 4)) ^ aswz));
#pragma unroll
    for (int t = 0; t < NT; ++t) {
      s16x8 b = *(const s16x8*)(s + t * 512 + lane * 8);
      acc[t] = __builtin_amdgcn_mfma_f32_16x16x32_bf16(a, b, acc[t], 0, 0, 0);
    }
    slot = (slot == 2) ? 0 : slot + 1;
  }

#pragma unroll
  for (int t = 0; t < NT; ++t) {
    int ct  = w + ((tbase + t) << 3);
    int col = (ct << 4) + (lane & 15);
    float bb = bias_lds[col];
#pragma unroll
    for (int r = 0; r < 4; ++r) {
      int orow = (g << 2) + r;
      if (orow < RROWS) {              // rows 8..15 dup of 0..7: skip
        float v = acc[t][r] + bb;
        if (!VF) {
          v = fmaxf(v, 0.f);
          int byte = (orow * orowb + (col << 1)) ^ (orow << 4);
          *(ushort*)((char*)Outb + byte) = f2bf(v);
        } else {
          v = 1.0f - 2.0f * __builtin_amdgcn_rcpf(__expf(2.0f * v) + 1.0f);
          int e = col / 10, d = col - e * 10;
          atomicAdd(&vf[orow][e], v * dXs[orow][d]);
        }
      }
    }
  }
}

__global__ __launch_bounds__(512, 2) void cde_mfma(
    const float* __restrict__ x, const int* __restrict__ mask,
    const float* __restrict__ We, const float* __restrict__ be,
    const float* __restrict__ b0, const float* __restrict__ b1,
    const float* __restrict__ b2, const float* __restrict__ b3,
    const ushort* __restrict__ Wp, const float* __restrict__ dX,
    float* __restrict__ out) {
  const int tid  = threadIdx.x;
  const int lane = tid & 63;
  const int w    = tid >> 6;
  const int n0   = blockIdx.x * RROWS;

  __shared__ ushort A0[RROWS * 128];      // 2 KB, swizzled bf16
  __shared__ ushort H1[RROWS * 512];      // 8 KB
  __shared__ ushort H2[RROWS * 512];      // 8 KB
  __shared__ ushort RING[8][3 * 4 * 512]; // 96 KB: per-wave 3 slots x <=4 frags
  __shared__ float  BL[2816];             // b0|b1|b2|b3
  __shared__ float  vf[RROWS][128];       // fused contraction accumulator
  __shared__ float  dXs[RROWS][D_IN];

  float zreg[2], k1r[2], k2r[2], k3r[2];

  // biases -> LDS (once)
  {
    int i = tid;
    BL[i] = b0[i]; BL[512 + i] = b1[i]; BL[1024 + i] = b2[i];
    BL[1536 + i] = b3[i];
    BL[2048 + i] = b3[512 + i];
    if (tid < 256) BL[2560 + tid] = b3[1024 + tid];
  }

  // z0 = x[:,0,:] @ We^T + be   (2 (row,e) elements per thread)
#pragma unroll
  for (int q = 0; q < 2; ++q) {
    int idx = (q << 9) + tid;
    int e = idx & 127, row = idx >> 7;
    float acc = be[e];
    const float* xr = x + (n0 + row) * 160;
#pragma unroll
    for (int d = 0; d < 10; ++d) acc = fmaf(xr[d], We[e * 10 + d], acc);
    zreg[q] = acc;
    int byte = ((row << 8) + (e << 1)) ^ (row << 4);
    *(ushort*)((char*)A0 + byte) = f2bf(acc);
  }
  __syncthreads();

  ushort* ring = &RING[w][0];

#pragma unroll 1
  for (int s = 0; s < 15; ++s) {
#pragma unroll 1
    for (int st = 0; st < 4; ++st) {
      if (tid < RROWS * D_IN) {
        int p = (st < 3) ? (3 * s + st) : ((s < 14) ? (3 * s + 3) : 45);
        dXs[tid / 10][tid % 10] = dX[p * (N_AG * D_IN) + n0 * 10 + tid];
      }
      fc_ring<4, 4, false>(A0, 256, Wp + OFF_W0P, BL, H1, 1024, vf, dXs, ring, w, lane, 0);
      __syncthreads();
      fc_ring<16, 4, false>(H1, 1024, Wp + OFF_W1P, BL + 512, H2, 1024, vf, dXs, ring, w, lane, 0);
      __syncthreads();
      fc_ring<16, 4, false>(H2, 1024, Wp + OFF_W2P, BL + 1024, H1, 1024, vf, dXs, ring, w, lane, 0);
      // zero vf for this stage's contraction (disjoint; synced below)
      ((float*)vf)[tid] = 0.f;
      ((float*)vf)[512 + tid] = 0.f;
      __syncthreads();
      fc_ring<16, 4, true>(H1, 1024, Wp + OFF_W3P, BL + 1536, nullptr, 0, vf, dXs, ring, w, lane, 0);
      fc_ring<16, 4, true>(H1, 1024, Wp + OFF_W3P, BL + 1536, nullptr, 0, vf, dXs, ring, w, lane, 4);
      fc_ring<16, 2, true>(H1, 1024, Wp + OFF_W3P, BL + 1536, nullptr, 0, vf, dXs, ring, w, lane, 8);
      __syncthreads();

      // RK4 (3/8 rule), state in registers
#pragma unroll
      for (int q = 0; q < 2; ++q) {
        int idx = (q << 9) + tid;
        int e = idx & 127, row = idx >> 7;
        float dv = vf[row][e];
        float z = zreg[q], zin;
        if (st == 0)      { k1r[q] = dv; zin = z + dv * (1.f / 3.f); }
        else if (st == 1) { k2r[q] = dv; zin = z + dv - k1r[q] * (1.f / 3.f); }
        else if (st == 2) { k3r[q] = dv; zin = z + k1r[q] - k2r[q] + dv; }
        else {
          z += (k1r[q] + 3.f * (k2r[q] + k3r[q]) + dv) * 0.125f;
          zreg[q] = z; zin = z;
        }
        int byte = ((row << 8) + (e << 1)) ^ (row << 4);
        *(ushort*)((char*)A0 + byte) = f2bf(zin);
      }
      __syncthreads();
    }
  }

#pragma unroll
  for (int q = 0; q < 2; ++q) {
    int idx = (q << 9) + tid;
    int e = idx & 127, row = idx >> 7;
    out[(n0 + row) * 128 + e] = (mask[n0 + row] != 0) ? zreg[q] : 0.f;
  }
}

extern "C" void kernel_launch(void* const* d_in, const int* in_sizes, int n_in,
                              void* d_out, int out_size, void* d_ws, size_t ws_size,
                              hipStream_t stream) {
  const float* x    = (const float*)d_in[1];
  const int*   mask = (const int*)d_in[2];
  const float* We   = (const float*)d_in[3];
  const float* be   = (const float*)d_in[4];
  const float* W0   = (const float*)d_in[5];
  const float* b0   = (const float*)d_in[6];
  const float* W1   = (const float*)d_in[7];
  const float* b1   = (const float*)d_in[8];
  const float* W2   = (const float*)d_in[9];
  const float* b2   = (const float*)d_in[10];
  const float* W3   = (const float*)d_in[11];
  const float* b3   = (const float*)d_in[12];
  float* out = (float*)d_out;

  ushort* wp = (ushort*)d_ws;
  float*  dX = (float*)((char*)d_ws + (size_t)OFF_END * 2);

  pack_w<<<(128 * 512 + 255) / 256, 256, 0, stream>>>(W0, wp + OFF_W0P, 512, 128);
  pack_w<<<(512 * 512 + 255) / 256, 256, 0, stream>>>(W1, wp + OFF_W1P, 512, 512);
  pack_w<<<(512 * 512 + 255) / 256, 256, 0, stream>>>(W2, wp + OFF_W2P, 512, 512);
  pack_w<<<(512 * 1280 + 255) / 256, 256, 0, stream>>>(W3, wp + OFF_W3P, 1280, 512);
  spline_dx_k<<<(N_AG * D_IN + 255) / 256, 256, 0, stream>>>(x, dX);
  cde_mfma<<<256, 512, 0, stream>>>(x, mask, We, be, b0, b1, b2, b3, wp, dX, out);
}

// Round 12
// 2979.571 us; speedup vs baseline: 2.3010x; 1.0461x over previous
//
#include <hip/hip_runtime.h>
#include <hip/hip_bf16.h>

// Neural CDE forward, R12: R7 structure (256 blocks x 512 thr x 8 rows, fused-VF,
// spill-free, best=2333us) + per-block K-rotation to decorrelate the weight
// stream across CUs. Theory: all 32 CUs/XCD read the SAME packed-weight bytes
// in near-lockstep -> L2 bank serialization; rotating each block's ks start
// (ks = (i + blockIdx%KS) % KS) spreads concurrent requests across the weight
// buffer -> full L2 bank parallelism. Everything else R7-verbatim.
// Layers via mfma_f32_16x16x32_bf16, dup-row A (row=lane&7; C rows 8..15 dup,
// skipped). L3 fuses tanh + D-contraction via LDS atomicAdd into vf[8][128].
// RK4 (3/8) state in registers.

typedef __attribute__((ext_vector_type(4))) float f32x4;
typedef __attribute__((ext_vector_type(8))) short s16x8;

#define N_AG  2048
#define D_IN  10
#define NPTS  46
#define RROWS 8

#define OFF_W0P 0
#define OFF_W1P (128 * 512)
#define OFF_W2P (OFF_W1P + 512 * 512)
#define OFF_W3P (OFF_W2P + 512 * 512)
#define OFF_END (OFF_W3P + 512 * 1280)   // ushorts

__device__ __forceinline__ ushort f2bf(float v) {
  __hip_bfloat16 h = __float2bfloat16(v);
  return *reinterpret_cast<ushort*>(&h);
}

// Pack W (O x K fp32, row-major) into MFMA B-fragment order (verified R2-R11):
// packed[((ct*KS+ks)*64 + lane)*8 + j] = bf16(W[col][k]),
// col = ct*16 + (lane&15), k = ks*32 + (lane>>4)*8 + j.
__global__ void pack_w(const float* __restrict__ W, ushort* __restrict__ Wp,
                       int O, int K) {
  int idx = blockIdx.x * blockDim.x + threadIdx.x;
  if (idx >= O * K) return;
  int j    = idx & 7;
  int lane = (idx >> 3) & 63;
  int rest = idx >> 9;
  int KS   = K >> 5;
  int ks   = rest % KS;
  int ct   = rest / KS;
  int col  = (ct << 4) + (lane & 15);
  int k    = (ks << 5) + ((lane >> 4) << 3) + j;
  Wp[idx]  = f2bf(W[col * K + k]);
}

// Natural cubic spline derivative table (verified R1-R11).
__global__ void spline_dx_k(const float* __restrict__ x, float* __restrict__ dX) {
  int idx = blockIdx.x * blockDim.x + threadIdx.x;
  if (idx >= N_AG * D_IN) return;
  int n = idx / D_IN;
  int d = idx - n * D_IN;

  float xv[16];
#pragma unroll
  for (int t = 0; t < 16; ++t) xv[t] = x[n * 160 + t * 10 + d];

  float cp[15], dp[15], M[16];
  {
    float rhs = 6.0f * (xv[2] - 2.0f * xv[1] + xv[0]);
    cp[1] = 0.25f;
    dp[1] = rhs * 0.25f;
#pragma unroll
    for (int i = 2; i <= 14; ++i) {
      rhs = 6.0f * (xv[i + 1] - 2.0f * xv[i] + xv[i - 1]);
      float m = 1.0f / (4.0f - cp[i - 1]);
      cp[i] = m;
      dp[i] = (rhs - dp[i - 1]) * m;
    }
    M[0] = 0.0f; M[15] = 0.0f;
    M[14] = dp[14];
#pragma unroll
    for (int i = 13; i >= 1; --i) M[i] = dp[i] - cp[i] * M[i + 1];
  }

#pragma unroll
  for (int p = 0; p < NPTS; ++p) {
    int i; float u;
    if (p < 45) { i = p / 3; u = (float)(p % 3) * (1.0f / 3.0f); }
    else        { i = 14;    u = 1.0f; }
    float b = (xv[i + 1] - xv[i]) - (2.0f * M[i] + M[i + 1]) * (1.0f / 6.0f);
    dX[p * (N_AG * D_IN) + idx] = b + M[i] * u + (M[i + 1] - M[i]) * (u * u * 0.5f);
  }
}

// One FC slice: rows 0..7 x (KS*32) @ W-tile columns ct = w + (tbase+t)*8.
// ks iteration rotated by roff (per-block) to decorrelate L2 access phase.
// VF=false: relu -> swizzled bf16 store into Outb.
// VF=true : tanh -> vf[orow][col/10] += v * dXs[orow][col%10] (LDS atomic).
template <int KS, int NT, bool VF>
__device__ __forceinline__ void fc(const ushort* __restrict__ Ain, int arowb,
                                   const ushort* __restrict__ Wp,
                                   const float* __restrict__ bias_lds,
                                   ushort* __restrict__ Outb, int orowb,
                                   float (*__restrict__ vf)[128],
                                   const float (*__restrict__ dXs)[D_IN],
                                   int w, int lane, int tbase, int roff) {
  f32x4 acc[NT];
#pragma unroll
  for (int t = 0; t < NT; ++t) acc[t] = (f32x4){0.f, 0.f, 0.f, 0.f};

  const int row8 = lane & 7;
  const int g    = lane >> 4;
  const char* abase = (const char*)Ain + row8 * arowb;
  const int aswz = row8 << 4;

#pragma unroll 2
  for (int i = 0; i < KS; ++i) {
    const int ks = (i + roff) & (KS - 1);
    s16x8 a = *(const s16x8*)(abase + (((ks << 6) + (g << 4)) ^ aswz));
#pragma unroll
    for (int t = 0; t < NT; ++t) {
      int ct = w + ((tbase + t) << 3);
      s16x8 b = *(const s16x8*)(Wp + (((ct * KS + ks) * 64 + lane) << 3));
      acc[t] = __builtin_amdgcn_mfma_f32_16x16x32_bf16(a, b, acc[t], 0, 0, 0);
    }
  }

#pragma unroll
  for (int t = 0; t < NT; ++t) {
    int ct  = w + ((tbase + t) << 3);
    int col = (ct << 4) + (lane & 15);
    float bb = bias_lds[col];
#pragma unroll
    for (int r = 0; r < 4; ++r) {
      int orow = (g << 2) + r;
      if (orow < RROWS) {              // rows 8..15 are dup of 0..7: skip
        float v = acc[t][r] + bb;
        if (!VF) {
          v = fmaxf(v, 0.f);
          int byte = (orow * orowb + (col << 1)) ^ (orow << 4);
          *(ushort*)((char*)Outb + byte) = f2bf(v);
        } else {
          v = 1.0f - 2.0f * __builtin_amdgcn_rcpf(__expf(2.0f * v) + 1.0f);
          int e = col / 10, d = col - e * 10;
          atomicAdd(&vf[orow][e], v * dXs[orow][d]);
        }
      }
    }
  }
}

__global__ __launch_bounds__(512, 2) void cde_mfma(
    const float* __restrict__ x, const int* __restrict__ mask,
    const float* __restrict__ We, const float* __restrict__ be,
    const float* __restrict__ b0, const float* __restrict__ b1,
    const float* __restrict__ b2, const float* __restrict__ b3,
    const ushort* __restrict__ Wp, const float* __restrict__ dX,
    float* __restrict__ out) {
  const int tid  = threadIdx.x;
  const int lane = tid & 63;
  const int w    = tid >> 6;
  const int n0   = blockIdx.x * RROWS;
  const int roff16 = blockIdx.x & 15;   // per-block K-phase rotation
  const int roff4  = blockIdx.x & 3;

  __shared__ ushort A0[RROWS * 128];   // 2 KB, swizzled bf16
  __shared__ ushort H1[RROWS * 512];   // 8 KB
  __shared__ ushort H2[RROWS * 512];   // 8 KB
  __shared__ float  BL[2816];          // b0|b1|b2|b3
  __shared__ float  vf[RROWS][128];    // fused contraction accumulator
  __shared__ float  dXs[RROWS][D_IN];

  float zreg[2], k1r[2], k2r[2], k3r[2];

  // biases -> LDS (once)
  {
    int i = tid;
    BL[i] = b0[i]; BL[512 + i] = b1[i]; BL[1024 + i] = b2[i];
    BL[1536 + i] = b3[i];
    BL[2048 + i] = b3[512 + i];
    if (tid < 256) BL[2560 + tid] = b3[1024 + tid];
  }

  // z0 = x[:,0,:] @ We^T + be   (2 (row,e) elements per thread)
#pragma unroll
  for (int q = 0; q < 2; ++q) {
    int idx = (q << 9) + tid;
    int e = idx & 127, row = idx >> 7;
    float acc = be[e];
    const float* xr = x + (n0 + row) * 160;
#pragma unroll
    for (int d = 0; d < 10; ++d) acc = fmaf(xr[d], We[e * 10 + d], acc);
    zreg[q] = acc;
    int byte = ((row << 8) + (e << 1)) ^ (row << 4);
    *(ushort*)((char*)A0 + byte) = f2bf(acc);
  }
  __syncthreads();

#pragma unroll 1
  for (int s = 0; s < 15; ++s) {
#pragma unroll 1
    for (int st = 0; st < 4; ++st) {
      if (tid < RROWS * D_IN) {
        int p = (st < 3) ? (3 * s + st) : ((s < 14) ? (3 * s + 3) : 45);
        dXs[tid / 10][tid % 10] = dX[p * (N_AG * D_IN) + n0 * 10 + tid];
      }
      fc<4, 4, false>(A0, 256, Wp + OFF_W0P, BL, H1, 1024, vf, dXs, w, lane, 0, roff4);
      __syncthreads();
      fc<16, 4, false>(H1, 1024, Wp + OFF_W1P, BL + 512, H2, 1024, vf, dXs, w, lane, 0, roff16);
      __syncthreads();
      fc<16, 4, false>(H2, 1024, Wp + OFF_W2P, BL + 1024, H1, 1024, vf, dXs, w, lane, 0, roff16);
      // zero vf for this stage's contraction (disjoint; synced below)
      ((float*)vf)[tid] = 0.f;
      ((float*)vf)[512 + tid] = 0.f;
      __syncthreads();
      fc<16, 4, true>(H1, 1024, Wp + OFF_W3P, BL + 1536, nullptr, 0, vf, dXs, w, lane, 0, roff16);
      fc<16, 4, true>(H1, 1024, Wp + OFF_W3P, BL + 1536, nullptr, 0, vf, dXs, w, lane, 4, roff16);
      fc<16, 2, true>(H1, 1024, Wp + OFF_W3P, BL + 1536, nullptr, 0, vf, dXs, w, lane, 8, roff16);
      __syncthreads();

      // RK4 (3/8 rule), state in registers
#pragma unroll
      for (int q = 0; q < 2; ++q) {
        int idx = (q << 9) + tid;
        int e = idx & 127, row = idx >> 7;
        float dv = vf[row][e];
        float z = zreg[q], zin;
        if (st == 0)      { k1r[q] = dv; zin = z + dv * (1.f / 3.f); }
        else if (st == 1) { k2r[q] = dv; zin = z + dv - k1r[q] * (1.f / 3.f); }
        else if (st == 2) { k3r[q] = dv; zin = z + k1r[q] - k2r[q] + dv; }
        else {
          z += (k1r[q] + 3.f * (k2r[q] + k3r[q]) + dv) * 0.125f;
          zreg[q] = z; zin = z;
        }
        int byte = ((row << 8) + (e << 1)) ^ (row << 4);
        *(ushort*)((char*)A0 + byte) = f2bf(zin);
      }
      __syncthreads();
    }
  }

#pragma unroll
  for (int q = 0; q < 2; ++q) {
    int idx = (q << 9) + tid;
    int e = idx & 127, row = idx >> 7;
    out[(n0 + row) * 128 + e] = (mask[n0 + row] != 0) ? zreg[q] : 0.f;
  }
}

extern "C" void kernel_launch(void* const* d_in, const int* in_sizes, int n_in,
                              void* d_out, int out_size, void* d_ws, size_t ws_size,
                              hipStream_t stream) {
  const float* x    = (const float*)d_in[1];
  const int*   mask = (const int*)d_in[2];
  const float* We   = (const float*)d_in[3];
  const float* be   = (const float*)d_in[4];
  const float* W0   = (const float*)d_in[5];
  const float* b0   = (const float*)d_in[6];
  const float* W1   = (const float*)d_in[7];
  const float* b1   = (const float*)d_in[8];
  const float* W2   = (const float*)d_in[9];
  const float* b2   = (const float*)d_in[10];
  const float* W3   = (const float*)d_in[11];
  const float* b3   = (const float*)d_in[12];
  float* out = (float*)d_out;

  ushort* wp = (ushort*)d_ws;
  float*  dX = (float*)((char*)d_ws + (size_t)OFF_END * 2);

  pack_w<<<(128 * 512 + 255) / 256, 256, 0, stream>>>(W0, wp + OFF_W0P, 512, 128);
  pack_w<<<(512 * 512 + 255) / 256, 256, 0, stream>>>(W1, wp + OFF_W1P, 512, 512);
  pack_w<<<(512 * 512 + 255) / 256, 256, 0, stream>>>(W2, wp + OFF_W2P, 512, 512);
  pack_w<<<(512 * 1280 + 255) / 256, 256, 0, stream>>>(W3, wp + OFF_W3P, 1280, 512);
  spline_dx_k<<<(N_AG * D_IN + 255) / 256, 256, 0, stream>>>(x, dX);
  cde_mfma<<<256, 512, 0, stream>>>(x, mask, We, be, b0, b1, b2, b3, wp, dX, out);
}